// Round 2
// baseline (778.915 us; speedup 1.0000x reference)
//
#include <hip/hip_runtime.h>
#include <hip/hip_fp16.h>

typedef _Float16 f16;
typedef _Float16 f16x8 __attribute__((ext_vector_type(8)));
typedef _Float16 f16x2 __attribute__((ext_vector_type(2)));
typedef float    f32x4 __attribute__((ext_vector_type(4)));
typedef unsigned long long u64;
typedef unsigned int u32;

#define HIDDEN 128
#define G3     384   // 3*HIDDEN

// ---------------- small device helpers ----------------

#if __has_builtin(__builtin_amdgcn_fdot2)
__device__ inline float fdot2f(f16x2 a, f16x2 b, float c) {
  return __builtin_amdgcn_fdot2(a, b, c, false);
}
#else
__device__ inline float fdot2f(f16x2 a, f16x2 b, float c) {
  return c + (float)a[0] * (float)b[0] + (float)a[1] * (float)b[1];
}
#endif

__device__ inline float dot8(f16x8 w, f16x8 h, float c) {
  c = fdot2f((f16x2){w[0], w[1]}, (f16x2){h[0], h[1]}, c);
  c = fdot2f((f16x2){w[2], w[3]}, (f16x2){h[2], h[3]}, c);
  c = fdot2f((f16x2){w[4], w[5]}, (f16x2){h[4], h[5]}, c);
  c = fdot2f((f16x2){w[6], w[7]}, (f16x2){h[6], h[7]}, c);
  return c;
}

__device__ inline float sigm(float x) { return 1.f / (1.f + __expf(-x)); }
__device__ inline float tanh_f(float x) {
  float ax = fabsf(x);
  float e  = __expf(2.f * ax);
  float r  = 1.f - 2.f / (e + 1.f);   // overflow -> 1.0, graceful
  return x < 0.f ? -r : r;
}

// ---------------- sorting pipeline ----------------

__global__ void hist_kernel(const int* __restrict__ idx, int* __restrict__ counts, int N) {
  int i = blockIdx.x * blockDim.x + threadIdx.x;
  if (i < N) atomicAdd(&counts[idx[i]], 1);
}

__global__ __launch_bounds__(1024) void scan_kernel(const int* __restrict__ counts,
                                                    int* __restrict__ off, int dim) {
  __shared__ int buf[1024];
  __shared__ int carry;
  const int tid = threadIdx.x;
  if (tid == 0) carry = 0;
  __syncthreads();
  for (int base = 0; base < dim; base += 1024) {
    int i = base + tid;
    int x = (i < dim) ? counts[i] : 0;
    buf[tid] = x;
    __syncthreads();
    for (int ofs = 1; ofs < 1024; ofs <<= 1) {
      int v = 0;
      if (tid >= ofs) v = buf[tid - ofs];
      __syncthreads();
      buf[tid] += v;
      __syncthreads();
    }
    if (i < dim) off[i] = carry + buf[tid] - x;  // exclusive
    __syncthreads();
    if (tid == 1023) carry += buf[1023];
    __syncthreads();
  }
  if (tid == 0) off[dim] = carry;
}

__global__ void scatter_kernel(const float* __restrict__ t, const int* __restrict__ idx,
                               const int* __restrict__ off, int* __restrict__ cursor,
                               u64* __restrict__ keys, int N) {
  int i = blockIdx.x * blockDim.x + threadIdx.x;
  if (i >= N) return;
  int g = idx[i];
  int p = off[g] + atomicAdd(&cursor[g], 1);
  // t in [0,1): positive-float bits are order-preserving as uint. Tie-break by
  // original index => exact match of stable lexsort((t, index)).
  keys[p] = ((u64)__float_as_uint(t[i]) << 32) | (u32)i;
}

__global__ void sortg_kernel(const int* __restrict__ off, const int* __restrict__ cnt,
                             u64* __restrict__ keys, int dim) {
  int g = blockIdx.x * blockDim.x + threadIdx.x;
  if (g >= dim) return;
  int s = off[g], m = cnt[g];
  for (int i = 1; i < m; i++) {           // groups ~Poisson(20): O(m^2) is fine
    u64 k = keys[s + i];
    int j = i - 1;
    while (j >= 0 && keys[s + j] > k) { keys[s + j + 1] = keys[s + j]; j--; }
    keys[s + j + 1] = k;
  }
}

// ---------------- gi = msg @ W_ih^T + b_ih  (MFMA f16, 128x128 tile) ----------------
// f32 inputs are converted to f16 during LDS staging (no separate cvt pass).

__global__ __launch_bounds__(256) void gi_gemm(const float* __restrict__ A32,  // [N][128] msg f32
                                               const float* __restrict__ B32,  // [384][128] W_ih f32
                                               const float* __restrict__ b_ih,
                                               f16* __restrict__ GI,           // [N][384]
                                               int N) {
  __shared__ __align__(16) f16 As[128 * 128];
  __shared__ __align__(16) f16 Bs[128 * 128];
  const int tid = threadIdx.x;
  const int m0 = blockIdx.x * 128;
  const int n0 = blockIdx.y * 128;
  // stage: 2048 f16x8 chunks per tile, 8 per thread; chunk v -> row=v>>4, col=(v&15)*8
  for (int q = 0; q < 8; q++) {
    int v = tid + q * 256;
    int row = v >> 4;
    int col = (v & 15) * 8;
    int gr = m0 + row; if (gr >= N) gr = N - 1;   // clamp; stores are guarded
    const float4 a0 = *(const float4*)(A32 + (size_t)gr * 128 + col);
    const float4 a1 = *(const float4*)(A32 + (size_t)gr * 128 + col + 4);
    ((f16x8*)As)[v] = (f16x8){(f16)a0.x, (f16)a0.y, (f16)a0.z, (f16)a0.w,
                              (f16)a1.x, (f16)a1.y, (f16)a1.z, (f16)a1.w};
    const float4 b0 = *(const float4*)(B32 + (size_t)(n0 + row) * 128 + col);
    const float4 b1 = *(const float4*)(B32 + (size_t)(n0 + row) * 128 + col + 4);
    ((f16x8*)Bs)[v] = (f16x8){(f16)b0.x, (f16)b0.y, (f16)b0.z, (f16)b0.w,
                              (f16)b1.x, (f16)b1.y, (f16)b1.z, (f16)b1.w};
  }
  __syncthreads();
  const int wave = tid >> 6, lane = tid & 63;
  const int wm = (wave >> 1) * 64, wn = (wave & 1) * 64;
  const int fr = lane & 15, kg = lane >> 4;
  f32x4 acc[4][4];
#pragma unroll
  for (int i = 0; i < 4; i++)
#pragma unroll
    for (int j = 0; j < 4; j++) acc[i][j] = (f32x4){0.f, 0.f, 0.f, 0.f};
#pragma unroll
  for (int kc = 0; kc < 4; kc++) {
    f16x8 a[4], b[4];
#pragma unroll
    for (int mi = 0; mi < 4; mi++)
      a[mi] = *(const f16x8*)&As[(wm + mi * 16 + fr) * 128 + kc * 32 + kg * 8];
#pragma unroll
    for (int ni = 0; ni < 4; ni++)
      b[ni] = *(const f16x8*)&Bs[(wn + ni * 16 + fr) * 128 + kc * 32 + kg * 8];
#pragma unroll
    for (int mi = 0; mi < 4; mi++)
#pragma unroll
      for (int ni = 0; ni < 4; ni++)
        acc[mi][ni] = __builtin_amdgcn_mfma_f32_16x16x32_f16(a[mi], b[ni], acc[mi][ni], 0, 0, 0);
  }
  // C/D layout: col = lane&15, row = (lane>>4)*4 + q   [guide §3, m89-verified]
#pragma unroll
  for (int ni = 0; ni < 4; ni++) {
    int col = n0 + wn + ni * 16 + fr;
    float bi = b_ih[col];
#pragma unroll
    for (int mi = 0; mi < 4; mi++)
#pragma unroll
      for (int q = 0; q < 4; q++) {
        int row = m0 + wm + mi * 16 + kg * 4 + q;
        if (row < N) GI[(size_t)row * G3 + col] = (f16)(acc[mi][ni][q] + bi);
      }
  }
}

// ---------------- GRU recurrence: one wave per node chain ----------------
// LDS: W_hh f16 interleaved [k/8][j][8] (98304 B) + per-wave h mirror [16][128] f16 (4096 B)

__global__ __launch_bounds__(1024) void recurrence_kernel(
    const f16* __restrict__ GI, const u64* __restrict__ keys,
    const int* __restrict__ off, const int* __restrict__ cnt,
    const float* __restrict__ W_hh, const float* __restrict__ b_hh,
    float* __restrict__ h_node, int* __restrict__ ctr, int dim) {
  extern __shared__ __align__(16) char smem[];
  f16* Wl = (f16*)smem;                       // idx = (k>>3)*3072 + j*8 + (k&7)
  f16* hb = (f16*)(smem + 98304);             // [wave][128]
  for (int e = threadIdx.x; e < G3 * HIDDEN; e += 1024) {
    int j = e >> 7, k = e & 127;
    Wl[(k >> 3) * 3072 + j * 8 + (k & 7)] = (f16)W_hh[e];
  }
  __syncthreads();
  const int wave = threadIdx.x >> 6, lane = threadIdx.x & 63;
  f16* h16 = hb + wave * 128;
  float bh[6];
#pragma unroll
  for (int i = 0; i < 6; i++) bh[i] = b_hh[lane + 64 * i];

  while (true) {
    int g;
    if (lane == 0) g = atomicAdd(ctr, 1);
    g = __shfl(g, 0, 64);
    if (g >= dim) break;
    const int m = cnt[g];
    if (m == 0) continue;
    const int s = off[g];
    float hr0 = 0.f, hr1 = 0.f;
    *(f16x2*)&h16[lane * 2] = (f16x2){(f16)0.f, (f16)0.f};
    __builtin_amdgcn_wave_barrier();
    for (int st = 0; st < m; ++st) {
      const int mid = (int)(u32)keys[s + st];
      const f16* gir = GI + (size_t)mid * G3;
      float gi0 = (float)gir[lane];
      float gi1 = (float)gir[lane + 64];
      float gi2 = (float)gir[lane + 128];
      float gi3 = (float)gir[lane + 192];
      float gi4 = (float)gir[lane + 256];
      float gi5 = (float)gir[lane + 320];
      float a0 = bh[0], a1 = bh[1], a2 = bh[2], a3 = bh[3], a4 = bh[4], a5 = bh[5];
#pragma unroll 2
      for (int kc = 0; kc < 16; kc++) {
        f16x8 h8 = *(const f16x8*)&h16[kc * 8];          // broadcast read
        const f16* wb = Wl + kc * 3072 + lane * 8;        // 64 lanes x 16B contiguous
        a0 = dot8(*(const f16x8*)(wb),            h8, a0);
        a1 = dot8(*(const f16x8*)(wb + 64 * 8),   h8, a1);
        a2 = dot8(*(const f16x8*)(wb + 128 * 8),  h8, a2);
        a3 = dot8(*(const f16x8*)(wb + 192 * 8),  h8, a3);
        a4 = dot8(*(const f16x8*)(wb + 256 * 8),  h8, a4);
        a5 = dot8(*(const f16x8*)(wb + 320 * 8),  h8, a5);
      }
      float r0 = sigm(gi0 + a0);
      float r1 = sigm(gi1 + a1);
      float z0 = sigm(gi2 + a2);
      float z1 = sigm(gi3 + a3);
      float n0 = tanh_f(gi4 + r0 * a4);
      float n1 = tanh_f(gi5 + r1 * a5);
      hr0 = (1.f - z0) * n0 + z0 * hr0;
      hr1 = (1.f - z1) * n1 + z1 * hr1;
      h16[lane]      = (f16)hr0;
      h16[lane + 64] = (f16)hr1;
      __builtin_amdgcn_wave_barrier();
    }
    h_node[(size_t)g * HIDDEN + lane]      = hr0;
    h_node[(size_t)g * HIDDEN + lane + 64] = hr1;
  }
}

// ---------------- final MLP: out = h_node @ W_mlp^T + b_mlp (only cnt>0) ----------------

__global__ __launch_bounds__(128) void mlp_kernel(const float* __restrict__ h_node,
                                                  const float* __restrict__ W,
                                                  const float* __restrict__ bias,
                                                  const int* __restrict__ cnt,
                                                  float* __restrict__ out, int dim) {
  __shared__ float hs[8][128];
  const int o = threadIdx.x;
  const int g0 = blockIdx.x * 8;
#pragma unroll
  for (int r = 0; r < 8; r++) {
    int g = g0 + r;
    hs[r][o] = (g < dim && cnt[g] > 0) ? h_node[(size_t)g * 128 + o] : 0.f;
  }
  __syncthreads();
  float b = bias[o];
  float acc[8];
#pragma unroll
  for (int r = 0; r < 8; r++) acc[r] = b;
  for (int k = 0; k < 128; k++) {
    float wk = W[o * 128 + k];
#pragma unroll
    for (int r = 0; r < 8; r++) acc[r] += hs[r][k] * wk;
  }
#pragma unroll
  for (int r = 0; r < 8; r++) {
    int g = g0 + r;
    if (g < dim && cnt[g] > 0) out[(size_t)g * 128 + o] = acc[r];
  }
}

// ---------------- host ----------------

extern "C" void kernel_launch(void* const* d_in, const int* in_sizes, int n_in,
                              void* d_out, int out_size, void* d_ws, size_t ws_size,
                              hipStream_t stream) {
  const float* msg   = (const float*)d_in[0];
  const float* t     = (const float*)d_in[1];
  const int*   indx  = (const int*)d_in[2];
  const float* W_ih  = (const float*)d_in[4];
  const float* W_hh  = (const float*)d_in[5];
  const float* b_ih  = (const float*)d_in[6];
  const float* b_hh  = (const float*)d_in[7];
  const float* W_mlp = (const float*)d_in[8];
  const float* b_mlp = (const float*)d_in[9];
  float* out = (float*)d_out;
  const int N   = in_sizes[0] / 128;
  const int dim = out_size / 128;

  char* ws = (char*)d_ws;
  size_t o = 0;
  auto alloc = [&](size_t b) { size_t r = o; o = (o + b + 255) & ~(size_t)255; return r; };
  f16*   gi16   = (f16*)(ws + alloc((size_t)N * G3 * 2));       // 153.6 MB
  u64*   keys   = (u64*)(ws + alloc((size_t)N * 8));            // 1.6 MB
  float* h_node = (float*)(ws + alloc((size_t)dim * 128 * 4));  // 5.1 MB
  char*  meta   = ws + alloc((size_t)(2 * dim + 64) * 4);
  int* counts = (int*)meta;
  int* cursor = (int*)(meta + (size_t)dim * 4);
  int* ctr    = (int*)(meta + (size_t)2 * dim * 4);
  int* offs   = (int*)(ws + alloc((size_t)(dim + 1) * 4));

  hipMemsetAsync(meta, 0, (size_t)(2 * dim + 64) * 4, stream);
  hipMemsetAsync(d_out, 0, (size_t)out_size * 4, stream);

  hist_kernel<<<(N + 255) / 256, 256, 0, stream>>>(indx, counts, N);
  scan_kernel<<<1, 1024, 0, stream>>>(counts, offs, dim);
  scatter_kernel<<<(N + 255) / 256, 256, 0, stream>>>(t, indx, offs, cursor, keys, N);
  sortg_kernel<<<(dim + 255) / 256, 256, 0, stream>>>(offs, counts, keys, dim);

  dim3 gg((N + 127) / 128, 3);
  gi_gemm<<<gg, 256, 0, stream>>>(msg, W_ih, b_ih, gi16, N);

  hipFuncSetAttribute(reinterpret_cast<const void*>(recurrence_kernel),
                      hipFuncAttributeMaxDynamicSharedMemorySize, 102400);
  recurrence_kernel<<<256, 1024, 102400, stream>>>(gi16, keys, offs, counts, W_hh, b_hh,
                                                   h_node, ctr, dim);
  mlp_kernel<<<(dim + 7) / 8, 128, 0, stream>>>(h_node, W_mlp, b_mlp, counts, out, dim);
}

// Round 3
// 667.697 us; speedup vs baseline: 1.1666x; 1.1666x over previous
//
#include <hip/hip_runtime.h>
#include <hip/hip_fp16.h>

typedef _Float16 f16;
typedef _Float16 f16x8 __attribute__((ext_vector_type(8)));
typedef _Float16 f16x4 __attribute__((ext_vector_type(4)));
typedef float    f32x4 __attribute__((ext_vector_type(4)));
typedef unsigned long long u64;
typedef unsigned int u32;

#define HIDDEN 128
#define G3     384   // 3*HIDDEN

__device__ inline float sigm(float x) { return 1.f / (1.f + __expf(-x)); }
__device__ inline float tanh_f(float x) {
  float ax = fabsf(x);
  float e  = __expf(2.f * ax);
  float r  = 1.f - 2.f / (e + 1.f);   // overflow -> 1.0, graceful
  return x < 0.f ? -r : r;
}

// ---------------- sorting pipeline ----------------

__global__ void hist_kernel(const int* __restrict__ idx, int* __restrict__ counts, int N) {
  int i = blockIdx.x * blockDim.x + threadIdx.x;
  if (i < N) atomicAdd(&counts[idx[i]], 1);
}

// shfl-based single-block exclusive scan; out[dim] = total. dim <= 16384.
__global__ __launch_bounds__(1024) void scan_generic(const int* __restrict__ in,
                                                     int* __restrict__ out, int dim) {
  __shared__ int wsum[16];
  __shared__ int wpre[16];
  const int tid = threadIdx.x, lane = tid & 63, wid = tid >> 6;
  const int base_i = tid * 16;
  int loc[16];
  int s = 0;
#pragma unroll
  for (int u = 0; u < 16; u++) {
    int i = base_i + u;
    int x = (i < dim) ? in[i] : 0;
    loc[u] = s; s += x;
  }
  int inc = s;
#pragma unroll
  for (int d = 1; d < 64; d <<= 1) { int v = __shfl_up(inc, d, 64); if (lane >= d) inc += v; }
  if (lane == 63) wsum[wid] = inc;
  __syncthreads();
  if (wid == 0 && lane < 16) {
    int v = wsum[lane];
    int p = v;
#pragma unroll
    for (int d = 1; d < 16; d <<= 1) { int q = __shfl_up(p, d, 16); if (lane >= d) p += q; }
    wpre[lane] = p - v;
  }
  __syncthreads();
  const int excl = wpre[wid] + inc - s;
#pragma unroll
  for (int u = 0; u < 16; u++) {
    int i = base_i + u;
    if (i < dim) out[i] = excl + loc[u];
  }
  if (tid == 1023) out[dim] = excl + s;
}

__global__ void scatter_kernel(const float* __restrict__ t, const int* __restrict__ idx,
                               const int* __restrict__ off, int* __restrict__ cursor,
                               u64* __restrict__ keys, int* __restrict__ pos2g, int N) {
  int i = blockIdx.x * blockDim.x + threadIdx.x;
  if (i >= N) return;
  int g = idx[i];
  int p = off[g] + atomicAdd(&cursor[g], 1);
  // t in [0,1): positive-float bits are order-preserving as uint; tie-break by i
  keys[p] = ((u64)__float_as_uint(t[i]) << 32) | (u32)i;
  pos2g[p] = g;
}

// parallel rank-select: each message counts smaller keys within its group
__global__ void rank_kernel(const u64* __restrict__ keys, const int* __restrict__ pos2g,
                            const int* __restrict__ off, const int* __restrict__ cnt,
                            u64* __restrict__ keys2, int N) {
  int p = blockIdx.x * blockDim.x + threadIdx.x;
  if (p >= N) return;
  int g = pos2g[p];
  int s = off[g], m = cnt[g];
  u64 k = keys[p];
  int r = 0;
  for (int q = 0; q < m; q++) r += (keys[s + q] < k);
  keys2[s + r] = k;
}

// length binning (descending) for batch packing
__global__ void lenbin_kernel(const int* __restrict__ cnt, int* __restrict__ lhist, int dim) {
  int g = blockIdx.x * blockDim.x + threadIdx.x;
  if (g >= dim) return;
  int b = 511 - min(cnt[g], 511);
  atomicAdd(&lhist[b], 1);
}

__global__ void lenscatter_kernel(const int* __restrict__ cnt, const int* __restrict__ loff,
                                  int* __restrict__ lcur, int* __restrict__ order, int dim) {
  int g = blockIdx.x * blockDim.x + threadIdx.x;
  if (g >= dim) return;
  int b = 511 - min(cnt[g], 511);
  int p = loff[b] + atomicAdd(&lcur[b], 1);
  order[p] = g;
}

// ---------------- gi = msg @ W_ih^T + bias  (MFMA f16, 128x384 tile) ----------------
// bias = b_ih + b_hh for r,z rows (<256); b_ih only for n rows (b_hh_n stays with matvec).

__global__ __launch_bounds__(512, 2) void gi_gemm(const float* __restrict__ A32,  // [N][128]
                                                  const float* __restrict__ B32,  // [384][128]
                                                  const float* __restrict__ b_ih,
                                                  const float* __restrict__ b_hh,
                                                  f16* __restrict__ GI,           // [N][384]
                                                  int N) {
  extern __shared__ __align__(16) char smem_g[];
  f16* As = (f16*)smem_g;            // 128*128 = 32 KB
  f16* Bs = (f16*)(smem_g + 32768);  // 384*128 = 96 KB
  const int tid = threadIdx.x;
  const int m0 = blockIdx.x * 128;
#pragma unroll
  for (int it = 0; it < 4; it++) {   // A tile
    int v = tid + it * 512;
    int row = v >> 4, col = (v & 15) * 8;
    int gr = m0 + row; if (gr >= N) gr = N - 1;
    const float4 a0 = *(const float4*)(A32 + (size_t)gr * 128 + col);
    const float4 a1 = *(const float4*)(A32 + (size_t)gr * 128 + col + 4);
    ((f16x8*)As)[v] = (f16x8){(f16)a0.x, (f16)a0.y, (f16)a0.z, (f16)a0.w,
                              (f16)a1.x, (f16)a1.y, (f16)a1.z, (f16)a1.w};
  }
#pragma unroll
  for (int it = 0; it < 12; it++) {  // B = all 384 rows of W_ih
    int v = tid + it * 512;
    int row = v >> 4, col = (v & 15) * 8;
    const float4 b0 = *(const float4*)(B32 + (size_t)row * 128 + col);
    const float4 b1 = *(const float4*)(B32 + (size_t)row * 128 + col + 4);
    ((f16x8*)Bs)[v] = (f16x8){(f16)b0.x, (f16)b0.y, (f16)b0.z, (f16)b0.w,
                              (f16)b1.x, (f16)b1.y, (f16)b1.z, (f16)b1.w};
  }
  __syncthreads();
  const int wave = tid >> 6, lane = tid & 63;
  const int wm = (wave >> 1) * 32, wn = (wave & 1) * 192;
  const int fr = lane & 15, kg = lane >> 4;
  f32x4 acc[2][12];
#pragma unroll
  for (int i = 0; i < 2; i++)
#pragma unroll
    for (int j = 0; j < 12; j++) acc[i][j] = (f32x4){0.f, 0.f, 0.f, 0.f};
#pragma unroll
  for (int kc = 0; kc < 4; kc++) {
    f16x8 a[2], b[12];
#pragma unroll
    for (int mi = 0; mi < 2; mi++)
      a[mi] = *(const f16x8*)&As[(wm + mi * 16 + fr) * 128 + kc * 32 + kg * 8];
#pragma unroll
    for (int ni = 0; ni < 12; ni++)
      b[ni] = *(const f16x8*)&Bs[(wn + ni * 16 + fr) * 128 + kc * 32 + kg * 8];
#pragma unroll
    for (int mi = 0; mi < 2; mi++)
#pragma unroll
      for (int ni = 0; ni < 12; ni++)
        acc[mi][ni] = __builtin_amdgcn_mfma_f32_16x16x32_f16(a[mi], b[ni], acc[mi][ni], 0, 0, 0);
  }
  // C/D: col = lane&15, row = (lane>>4)*4 + q
#pragma unroll
  for (int ni = 0; ni < 12; ni++) {
    int col = wn + ni * 16 + fr;
    float bi = b_ih[col] + (col < 256 ? b_hh[col] : 0.f);
#pragma unroll
    for (int mi = 0; mi < 2; mi++)
#pragma unroll
      for (int q = 0; q < 4; q++) {
        int row = m0 + wm + mi * 16 + kg * 4 + q;
        if (row < N) GI[(size_t)row * G3 + col] = (f16)(acc[mi][ni][q] + bi);
      }
  }
}

// ---------------- batched GRU recurrence: 16 chains per wave via MFMA ----------------
// gh^T = W_hh(384x128) @ h^T(128x16): A = W_hh frags from LDS, B = h frags (LDS bounce),
// C col = chain, row = weight-row j. C-init: gi chunks (r,z) / b_hh_n (n). MLP fused at end.

__global__ __launch_bounds__(256) void recur2(
    const f16* __restrict__ GI, const u64* __restrict__ keys,
    const int* __restrict__ off, const int* __restrict__ cnt,
    const float* __restrict__ W_hh, const float* __restrict__ b_hh,
    const float* __restrict__ W_mlp, const float* __restrict__ b_mlp,
    const int* __restrict__ order, float* __restrict__ out, int dim, int nb) {
  extern __shared__ __align__(16) char smem[];
  f16* Wl = (f16*)smem;             // 96 KB: frag (mt*4+kt): 64 lanes x 16B, lane=(kchunk<<4)|row
  f16* hl = (f16*)(smem + 98304);   // 4 KB per wave: [c][j] f16, t-cell XOR-swizzled by c&7
  for (int v = threadIdx.x; v < 6144; v += 256) {
    int j = v >> 4, k8 = v & 15;          // k = k8*8
    const float* src = W_hh + (size_t)j * 128 + k8 * 8;
    const float4 s0 = *(const float4*)src;
    const float4 s1 = *(const float4*)(src + 4);
    f16x8 w = {(f16)s0.x, (f16)s0.y, (f16)s0.z, (f16)s0.w,
               (f16)s1.x, (f16)s1.y, (f16)s1.z, (f16)s1.w};
    int frag = (j >> 4) * 4 + (k8 >> 2);
    int lanepos = (k8 & 3) * 16 + (j & 15);
    *(f16x8*)(Wl + frag * 512 + lanepos * 8) = w;
  }
  __syncthreads();
  const int wid = threadIdx.x >> 6, lane = threadIdx.x & 63;
  const int w = wid * gridDim.x + blockIdx.x;   // stripe batch ranks across CUs
  if (w >= nb) return;
  f16* hw = hl + wid * 2048;
  const int c = lane & 15, hi = lane >> 4;
  const int oidx = w * 16 + c;
  const int valid = (oidx < dim);
  const int g = valid ? order[oidx] : 0;
  const int m = valid ? cnt[g] : 0;
  const int s = valid ? off[g] : 0;
  int L = m;
#pragma unroll
  for (int d = 1; d < 16; d <<= 1) L = max(L, __shfl_xor(L, d, 16));

  f32x4 bhn[8];
#pragma unroll
  for (int t = 0; t < 8; t++) bhn[t] = *(const f32x4*)(b_hh + 256 + t * 16 + hi * 4);

  // h = 0 (f32 master in regs + f16 LDS mirror)
  f32x4 hC[8];
#pragma unroll
  for (int t = 0; t < 8; t++) {
    hC[t] = (f32x4){0.f, 0.f, 0.f, 0.f};
    *(f16x4*)(hw + c * 128 + ((t ^ (c & 7)) * 16) + hi * 4) = (f16x4){(f16)0.f, (f16)0.f, (f16)0.f, (f16)0.f};
  }
  const u32* keysLo = (const u32*)keys;
  u32 mid = keysLo[2 * ((m > 0) ? s : 0)];

  for (int st = 0; st < L; ++st) {
    // prefetch next key
    int pos1 = (st + 1 < m) ? (s + st + 1) : 0;
    u32 midn = keysLo[2 * pos1];
    // gi chunks for current step (lane covers rows hi*4+q of each tile)
    const f16* gp = GI + (size_t)mid * G3 + hi * 4;
    f16x4 rz[16], gn[8];
#pragma unroll
    for (int t = 0; t < 16; t++) rz[t] = *(const f16x4*)(gp + t * 16);
#pragma unroll
    for (int t = 0; t < 8; t++) gn[t] = *(const f16x4*)(gp + 256 + t * 16);
    // B frags (h of 16 chains) from swizzled LDS
    f16x8 B[4];
#pragma unroll
    for (int kt = 0; kt < 4; kt++) {
      int tsrc = 2 * kt + (hi >> 1);
      B[kt] = *(const f16x8*)(hw + c * 128 + ((tsrc ^ (c & 7)) * 16) + (hi & 1) * 8);
    }
    // C-init: r,z tiles from gi (incl b_ih+b_hh); n tiles from b_hh_n
    f32x4 C[24];
#pragma unroll
    for (int t = 0; t < 16; t++)
      C[t] = (f32x4){(float)rz[t][0], (float)rz[t][1], (float)rz[t][2], (float)rz[t][3]};
#pragma unroll
    for (int t = 0; t < 8; t++) C[16 + t] = bhn[t];
    // gh += W_hh @ h
#pragma unroll
    for (int mt = 0; mt < 24; mt++)
#pragma unroll
      for (int kt = 0; kt < 4; kt++) {
        f16x8 A = *(const f16x8*)(Wl + (mt * 4 + kt) * 512 + lane * 8);
        C[mt] = __builtin_amdgcn_mfma_f32_16x16x32_f16(A, B[kt], C[mt], 0, 0, 0);
      }
    // gates + h update (freeze finished chains)
    const bool act = (st < m);
#pragma unroll
    for (int t = 0; t < 8; t++) {
      f32x4 hnew;
#pragma unroll
      for (int q = 0; q < 4; q++) {
        float r = sigm(C[t][q]);
        float z = sigm(C[t + 8][q]);
        float inn = (float)gn[t][q];
        float n = tanh_f(inn + r * C[t + 16][q]);
        hnew[q] = (1.f - z) * n + z * hC[t][q];
        hC[t][q] = act ? hnew[q] : hC[t][q];
      }
      *(f16x4*)(hw + c * 128 + ((t ^ (c & 7)) * 16) + hi * 4) =
          (f16x4){(f16)hC[t][0], (f16)hC[t][1], (f16)hC[t][2], (f16)hC[t][3]};
    }
    mid = midn;
  }

  // fused MLP: out = h @ W_mlp^T + b_mlp   (A = W_mlp f32->f16 from global, B = h)
  f16x8 Bf[4];
#pragma unroll
  for (int kt = 0; kt < 4; kt++) {
    int tsrc = 2 * kt + (hi >> 1);
    Bf[kt] = *(const f16x8*)(hw + c * 128 + ((tsrc ^ (c & 7)) * 16) + (hi & 1) * 8);
  }
  const bool do_store = valid && (m > 0);
#pragma unroll
  for (int mt = 0; mt < 8; mt++) {
    f32x4 o = *(const f32x4*)(b_mlp + mt * 16 + hi * 4);
#pragma unroll
    for (int kt = 0; kt < 4; kt++) {
      const float* wsrc = W_mlp + (size_t)(mt * 16 + c) * 128 + kt * 32 + hi * 8;
      const float4 w0 = *(const float4*)wsrc;
      const float4 w1 = *(const float4*)(wsrc + 4);
      f16x8 A = {(f16)w0.x, (f16)w0.y, (f16)w0.z, (f16)w0.w,
                 (f16)w1.x, (f16)w1.y, (f16)w1.z, (f16)w1.w};
      o = __builtin_amdgcn_mfma_f32_16x16x32_f16(A, Bf[kt], o, 0, 0, 0);
    }
    if (do_store) *(f32x4*)(out + (size_t)g * 128 + mt * 16 + hi * 4) = o;
  }
}

// ---------------- host ----------------

extern "C" void kernel_launch(void* const* d_in, const int* in_sizes, int n_in,
                              void* d_out, int out_size, void* d_ws, size_t ws_size,
                              hipStream_t stream) {
  const float* msg   = (const float*)d_in[0];
  const float* t     = (const float*)d_in[1];
  const int*   indx  = (const int*)d_in[2];
  const float* W_ih  = (const float*)d_in[4];
  const float* W_hh  = (const float*)d_in[5];
  const float* b_ih  = (const float*)d_in[6];
  const float* b_hh  = (const float*)d_in[7];
  const float* W_mlp = (const float*)d_in[8];
  const float* b_mlp = (const float*)d_in[9];
  float* out = (float*)d_out;
  const int N   = in_sizes[0] / 128;
  const int dim = out_size / 128;
  const int nb  = (dim + 15) / 16;

  char* ws = (char*)d_ws;
  size_t o = 0;
  auto alloc = [&](size_t b) { size_t r = o; o = (o + b + 255) & ~(size_t)255; return r; };
  f16* gi16   = (f16*)(ws + alloc((size_t)N * G3 * 2));   // 153.6 MB
  u64* keys   = (u64*)(ws + alloc((size_t)N * 8));        // 1.6 MB
  u64* keys2  = (u64*)(ws + alloc((size_t)N * 8));        // 1.6 MB
  int* pos2g  = (int*)(ws + alloc((size_t)N * 4));        // 0.8 MB
  int* offs   = (int*)(ws + alloc((size_t)(dim + 1) * 4));
  int* loff   = (int*)(ws + alloc(513 * 4));
  int* order  = (int*)(ws + alloc((size_t)dim * 4));
  size_t meta_bytes = (size_t)(2 * dim + 1024) * 4;
  char* meta  = ws + alloc(meta_bytes);
  int* counts = (int*)meta;
  int* cursor = (int*)(meta + (size_t)dim * 4);
  int* lhist  = (int*)(meta + (size_t)2 * dim * 4);
  int* lcur   = (int*)(meta + (size_t)(2 * dim + 512) * 4);

  hipMemsetAsync(meta, 0, meta_bytes, stream);
  hipMemsetAsync(d_out, 0, (size_t)out_size * 4, stream);

  const int gN = (N + 255) / 256, gD = (dim + 255) / 256;
  hist_kernel<<<gN, 256, 0, stream>>>(indx, counts, N);
  scan_generic<<<1, 1024, 0, stream>>>(counts, offs, dim);
  scatter_kernel<<<gN, 256, 0, stream>>>(t, indx, offs, cursor, keys, pos2g, N);
  rank_kernel<<<gN, 256, 0, stream>>>(keys, pos2g, offs, counts, keys2, N);
  lenbin_kernel<<<gD, 256, 0, stream>>>(counts, lhist, dim);
  scan_generic<<<1, 1024, 0, stream>>>(lhist, loff, 512);
  lenscatter_kernel<<<gD, 256, 0, stream>>>(counts, loff, lcur, order, dim);

  hipFuncSetAttribute(reinterpret_cast<const void*>(gi_gemm),
                      hipFuncAttributeMaxDynamicSharedMemorySize, 131072);
  gi_gemm<<<(N + 127) / 128, 512, 131072, stream>>>(msg, W_ih, b_ih, b_hh, gi16, N);

  hipFuncSetAttribute(reinterpret_cast<const void*>(recur2),
                      hipFuncAttributeMaxDynamicSharedMemorySize, 114688);
  const int rblocks = (nb + 3) / 4;   // 4 waves/block, one batch of 16 chains per wave
  recur2<<<rblocks, 256, 114688, stream>>>(gi16, keys2, offs, counts, W_hh, b_hh,
                                           W_mlp, b_mlp, order, out, dim, nb);
}

// Round 4
// 456.555 us; speedup vs baseline: 1.7061x; 1.4625x over previous
//
#include <hip/hip_runtime.h>
#include <hip/hip_fp16.h>

typedef _Float16 f16;
typedef _Float16 f16x8 __attribute__((ext_vector_type(8)));
typedef _Float16 f16x4 __attribute__((ext_vector_type(4)));
typedef float    f32x4 __attribute__((ext_vector_type(4)));
typedef unsigned long long u64;
typedef unsigned int u32;

#define HIDDEN 128
#define G3     384   // 3*HIDDEN

__device__ inline float sigm(float x) { return 1.f / (1.f + __expf(-x)); }
__device__ inline float tanh_f(float x) {
  float ax = fabsf(x);
  float e  = __expf(2.f * ax);
  float r  = 1.f - 2.f / (e + 1.f);   // overflow -> 1.0, graceful
  return x < 0.f ? -r : r;
}

// ---------------- sorting pipeline ----------------

__global__ void hist_kernel(const int* __restrict__ idx, int* __restrict__ counts, int N) {
  int i = blockIdx.x * blockDim.x + threadIdx.x;
  if (i < N) atomicAdd(&counts[idx[i]], 1);
}

// shfl-based single-block exclusive scan; out[dim] = total. dim <= 16384.
__global__ __launch_bounds__(1024) void scan_generic(const int* __restrict__ in,
                                                     int* __restrict__ out, int dim) {
  __shared__ int wsum[16];
  __shared__ int wpre[16];
  const int tid = threadIdx.x, lane = tid & 63, wid = tid >> 6;
  const int base_i = tid * 16;
  int loc[16];
  int s = 0;
#pragma unroll
  for (int u = 0; u < 16; u++) {
    int i = base_i + u;
    int x = (i < dim) ? in[i] : 0;
    loc[u] = s; s += x;
  }
  int inc = s;
#pragma unroll
  for (int d = 1; d < 64; d <<= 1) { int v = __shfl_up(inc, d, 64); if (lane >= d) inc += v; }
  if (lane == 63) wsum[wid] = inc;
  __syncthreads();
  if (wid == 0 && lane < 16) {
    int v = wsum[lane];
    int p = v;
#pragma unroll
    for (int d = 1; d < 16; d <<= 1) { int q = __shfl_up(p, d, 16); if (lane >= d) p += q; }
    wpre[lane] = p - v;
  }
  __syncthreads();
  const int excl = wpre[wid] + inc - s;
#pragma unroll
  for (int u = 0; u < 16; u++) {
    int i = base_i + u;
    if (i < dim) out[i] = excl + loc[u];
  }
  if (tid == 1023) out[dim] = excl + s;
}

__global__ void scatter_kernel(const float* __restrict__ t, const int* __restrict__ idx,
                               const int* __restrict__ off, int* __restrict__ cursor,
                               u64* __restrict__ keys, int* __restrict__ pos2g, int N) {
  int i = blockIdx.x * blockDim.x + threadIdx.x;
  if (i >= N) return;
  int g = idx[i];
  int p = off[g] + atomicAdd(&cursor[g], 1);
  // t in [0,1): positive-float bits are order-preserving as uint; tie-break by i
  keys[p] = ((u64)__float_as_uint(t[i]) << 32) | (u32)i;
  pos2g[p] = g;
}

// parallel rank-select: each message counts smaller keys within its group
__global__ void rank_kernel(const u64* __restrict__ keys, const int* __restrict__ pos2g,
                            const int* __restrict__ off, const int* __restrict__ cnt,
                            u64* __restrict__ keys2, int N) {
  int p = blockIdx.x * blockDim.x + threadIdx.x;
  if (p >= N) return;
  int g = pos2g[p];
  int s = off[g], m = cnt[g];
  u64 k = keys[p];
  int r = 0;
  for (int q = 0; q < m; q++) r += (keys[s + q] < k);
  keys2[s + r] = k;
}

// length binning (descending) for batch packing
__global__ void lenbin_kernel(const int* __restrict__ cnt, int* __restrict__ lhist, int dim) {
  int g = blockIdx.x * blockDim.x + threadIdx.x;
  if (g >= dim) return;
  int b = 511 - min(cnt[g], 511);
  atomicAdd(&lhist[b], 1);
}

__global__ void lenscatter_kernel(const int* __restrict__ cnt, const int* __restrict__ loff,
                                  int* __restrict__ lcur, int* __restrict__ order, int dim) {
  int g = blockIdx.x * blockDim.x + threadIdx.x;
  if (g >= dim) return;
  int b = 511 - min(cnt[g], 511);
  int p = loff[b] + atomicAdd(&lcur[b], 1);
  order[p] = g;
}

// ---------------- gi = msg @ W_ih^T + bias  (MFMA f16, 128x384 tile) ----------------
// bias = b_ih + b_hh for r,z rows (<256); b_ih only for n rows (b_hh_n stays with matvec).

__global__ __launch_bounds__(512, 2) void gi_gemm(const float* __restrict__ A32,  // [N][128]
                                                  const float* __restrict__ B32,  // [384][128]
                                                  const float* __restrict__ b_ih,
                                                  const float* __restrict__ b_hh,
                                                  f16* __restrict__ GI,           // [N][384]
                                                  int N) {
  extern __shared__ __align__(16) char smem_g[];
  f16* As = (f16*)smem_g;            // 128*128 = 32 KB
  f16* Bs = (f16*)(smem_g + 32768);  // 384*128 = 96 KB
  const int tid = threadIdx.x;
  const int m0 = blockIdx.x * 128;
#pragma unroll
  for (int it = 0; it < 4; it++) {   // A tile
    int v = tid + it * 512;
    int row = v >> 4, col = (v & 15) * 8;
    int gr = m0 + row; if (gr >= N) gr = N - 1;
    const float4 a0 = *(const float4*)(A32 + (size_t)gr * 128 + col);
    const float4 a1 = *(const float4*)(A32 + (size_t)gr * 128 + col + 4);
    ((f16x8*)As)[v] = (f16x8){(f16)a0.x, (f16)a0.y, (f16)a0.z, (f16)a0.w,
                              (f16)a1.x, (f16)a1.y, (f16)a1.z, (f16)a1.w};
  }
#pragma unroll
  for (int it = 0; it < 12; it++) {  // B = all 384 rows of W_ih
    int v = tid + it * 512;
    int row = v >> 4, col = (v & 15) * 8;
    const float4 b0 = *(const float4*)(B32 + (size_t)row * 128 + col);
    const float4 b1 = *(const float4*)(B32 + (size_t)row * 128 + col + 4);
    ((f16x8*)Bs)[v] = (f16x8){(f16)b0.x, (f16)b0.y, (f16)b0.z, (f16)b0.w,
                              (f16)b1.x, (f16)b1.y, (f16)b1.z, (f16)b1.w};
  }
  __syncthreads();
  const int wave = tid >> 6, lane = tid & 63;
  const int wm = (wave >> 1) * 32, wn = (wave & 1) * 192;
  const int fr = lane & 15, kg = lane >> 4;
  f32x4 acc[2][12];
#pragma unroll
  for (int i = 0; i < 2; i++)
#pragma unroll
    for (int j = 0; j < 12; j++) acc[i][j] = (f32x4){0.f, 0.f, 0.f, 0.f};
#pragma unroll
  for (int kc = 0; kc < 4; kc++) {
    f16x8 a[2], b[12];
#pragma unroll
    for (int mi = 0; mi < 2; mi++)
      a[mi] = *(const f16x8*)&As[(wm + mi * 16 + fr) * 128 + kc * 32 + kg * 8];
#pragma unroll
    for (int ni = 0; ni < 12; ni++)
      b[ni] = *(const f16x8*)&Bs[(wn + ni * 16 + fr) * 128 + kc * 32 + kg * 8];
#pragma unroll
    for (int mi = 0; mi < 2; mi++)
#pragma unroll
      for (int ni = 0; ni < 12; ni++)
        acc[mi][ni] = __builtin_amdgcn_mfma_f32_16x16x32_f16(a[mi], b[ni], acc[mi][ni], 0, 0, 0);
  }
  // C/D: col = lane&15, row = (lane>>4)*4 + q
#pragma unroll
  for (int ni = 0; ni < 12; ni++) {
    int col = wn + ni * 16 + fr;
    float bi = b_ih[col] + (col < 256 ? b_hh[col] : 0.f);
#pragma unroll
    for (int mi = 0; mi < 2; mi++)
#pragma unroll
      for (int q = 0; q < 4; q++) {
        int row = m0 + wm + mi * 16 + kg * 4 + q;
        if (row < N) GI[(size_t)row * G3 + col] = (f16)(acc[mi][ni][q] + bi);
      }
  }
}

// ---------------- batched GRU recurrence v3: one batch (16 chains) per block ----------------
// 4 waves cooperate; wave q owns gh tiles {2q,2q+1} of each gate part (r,z,n) = exactly the
// h-rows [32q,32q+32) it updates. W_hh A-frags permanently in registers (96 VGPR/wave).
// h crosses waves via 8 KB double-buffered LDS (f16, XOR-swizzled). One barrier per step.

__global__ __launch_bounds__(256) void recur3(
    const f16* __restrict__ GI, const u64* __restrict__ keys,
    const int* __restrict__ off, const int* __restrict__ cnt,
    const float* __restrict__ W_hh, const float* __restrict__ b_hh,
    const float* __restrict__ W_mlp, const float* __restrict__ b_mlp,
    const int* __restrict__ order, float* __restrict__ out, int dim) {
  __shared__ __align__(16) f16 hB[2][16 * 128];  // [parity][c][k] swizzled
  const int tid = threadIdx.x;
  const int wq = tid >> 6, lane = tid & 63;
  const int c = lane & 15, hi = lane >> 4;   // chain / row-quarter (also A-frag fr/kg)

  // ---- W_hh A-frags into registers: tiles {2q,2q+1, +8, +16} x kt 0..3 ----
  f16x8 A[6][4];
#pragma unroll
  for (int i = 0; i < 6; i++) {
    const int mt = 2 * wq + (i >> 1) * 8 + (i & 1);   // i: 0,1->r  2,3->z  4,5->n
#pragma unroll
    for (int kt = 0; kt < 4; kt++) {
      const float* src = W_hh + (size_t)(mt * 16 + c) * 128 + kt * 32 + hi * 8;
      const float4 s0 = *(const float4*)src;
      const float4 s1 = *(const float4*)(src + 4);
      A[i][kt] = (f16x8){(f16)s0.x, (f16)s0.y, (f16)s0.z, (f16)s0.w,
                         (f16)s1.x, (f16)s1.y, (f16)s1.z, (f16)s1.w};
    }
  }
  // n-gate bias for this wave's rows
  const f32x4 bhn0 = *(const f32x4*)(b_hh + 256 + (2 * wq) * 16 + hi * 4);
  const f32x4 bhn1 = *(const f32x4*)(b_hh + 256 + (2 * wq + 1) * 16 + hi * 4);

  // ---- chain metadata (per lane: chain c) ----
  const int oidx = blockIdx.x * 16 + c;
  const bool valid = (oidx < dim);
  const int g = valid ? order[oidx] : 0;
  const int m = valid ? cnt[g] : 0;
  const int s = valid ? off[g] : 0;
  int L = m;
#pragma unroll
  for (int d = 1; d < 16; d <<= 1) L = max(L, __shfl_xor(L, d, 16));

  // ---- init h = 0 (f32 master regs + LDS buf 0) ----
  float h0[8];
#pragma unroll
  for (int i = 0; i < 8; i++) h0[i] = 0.f;
  const f16x4 z4 = {(f16)0.f, (f16)0.f, (f16)0.f, (f16)0.f};
  *(f16x4*)&hB[0][c * 128 + (((2 * wq) ^ (c & 7)) * 16) + hi * 4] = z4;
  *(f16x4*)&hB[0][c * 128 + (((2 * wq + 1) ^ (c & 7)) * 16) + hi * 4] = z4;
  __syncthreads();

  const u32* keysLo = (const u32*)keys;
  const int go_r = 2 * wq * 16 + hi * 4;   // gi offset base (r part) for this lane's rows
  // gi for step 0 + key for step 1
  u32 mid = keysLo[2 * ((m > 0) ? s : 0)];
  const f16* gp0 = GI + (size_t)mid * G3 + go_r;
  f16x4 gr0 = *(const f16x4*)(gp0);
  f16x4 gr1 = *(const f16x4*)(gp0 + 16);
  f16x4 gz0 = *(const f16x4*)(gp0 + 128);
  f16x4 gz1 = *(const f16x4*)(gp0 + 144);
  f16x4 gn0 = *(const f16x4*)(gp0 + 256);
  f16x4 gn1 = *(const f16x4*)(gp0 + 272);
  u32 midn = keysLo[2 * ((m > 0) ? (s + min(1, m - 1)) : 0)];

  for (int st = 0; st < L; ++st) {
    // prefetch gi for st+1 and key for st+2
    const f16* gpn = GI + (size_t)midn * G3 + go_r;
    f16x4 ngr0 = *(const f16x4*)(gpn);
    f16x4 ngr1 = *(const f16x4*)(gpn + 16);
    f16x4 ngz0 = *(const f16x4*)(gpn + 128);
    f16x4 ngz1 = *(const f16x4*)(gpn + 144);
    f16x4 ngn0 = *(const f16x4*)(gpn + 256);
    f16x4 ngn1 = *(const f16x4*)(gpn + 272);
    u32 midn2 = keysLo[2 * ((m > 0) ? (s + min(st + 2, m - 1)) : 0)];

    // B frags: h of all 16 chains from LDS buf[st&1]
    const f16* hr = hB[st & 1];
    f16x8 B[4];
#pragma unroll
    for (int kt = 0; kt < 4; kt++)
      B[kt] = *(const f16x8*)&hr[c * 128 + (((2 * kt + (hi >> 1)) ^ (c & 7)) * 16) + (hi & 1) * 8];

    // gh tiles (C in registers; A in registers; zero C-init)
    f32x4 C[6];
#pragma unroll
    for (int i = 0; i < 6; i++) C[i] = (f32x4){0.f, 0.f, 0.f, 0.f};
#pragma unroll
    for (int i = 0; i < 6; i++)
#pragma unroll
      for (int kt = 0; kt < 4; kt++)
        C[i] = __builtin_amdgcn_mfma_f32_16x16x32_f16(A[i][kt], B[kt], C[i], 0, 0, 0);

    // gates for this wave's 8 h-rows (2 tiles x 4)
    const bool act = (st < m);
#pragma unroll
    for (int q_ = 0; q_ < 4; q_++) {
      float r = sigm((float)gr0[q_] + C[0][q_]);
      float z = sigm((float)gz0[q_] + C[2][q_]);
      float n = tanh_f((float)gn0[q_] + r * (C[4][q_] + bhn0[q_]));
      if (act) h0[q_] = (1.f - z) * n + z * h0[q_];
      float r2 = sigm((float)gr1[q_] + C[1][q_]);
      float z2 = sigm((float)gz1[q_] + C[3][q_]);
      float n2 = tanh_f((float)gn1[q_] + r2 * (C[5][q_] + bhn1[q_]));
      if (act) h0[4 + q_] = (1.f - z2) * n2 + z2 * h0[4 + q_];
    }
    // write new h into buf[(st+1)&1]
    f16* hw = hB[(st + 1) & 1];
    *(f16x4*)&hw[c * 128 + (((2 * wq) ^ (c & 7)) * 16) + hi * 4] =
        (f16x4){(f16)h0[0], (f16)h0[1], (f16)h0[2], (f16)h0[3]};
    *(f16x4*)&hw[c * 128 + (((2 * wq + 1) ^ (c & 7)) * 16) + hi * 4] =
        (f16x4){(f16)h0[4], (f16)h0[5], (f16)h0[6], (f16)h0[7]};
    __syncthreads();

    gr0 = ngr0; gr1 = ngr1; gz0 = ngz0; gz1 = ngz1; gn0 = ngn0; gn1 = ngn1;
    mid = midn; midn = midn2;
  }

  // ---- fused MLP: out = h @ W_mlp^T + b_mlp ; empty nodes -> 0 ----
  const f16* hf = hB[L & 1];
  f16x8 Bf[4];
#pragma unroll
  for (int kt = 0; kt < 4; kt++)
    Bf[kt] = *(const f16x8*)&hf[c * 128 + (((2 * kt + (hi >> 1)) ^ (c & 7)) * 16) + (hi & 1) * 8];
#pragma unroll
  for (int oi = 0; oi < 2; oi++) {
    const int ot = 2 * wq + oi;
    f32x4 o = *(const f32x4*)(b_mlp + ot * 16 + hi * 4);
#pragma unroll
    for (int kt = 0; kt < 4; kt++) {
      const float* wsrc = W_mlp + (size_t)(ot * 16 + c) * 128 + kt * 32 + hi * 8;
      const float4 w0 = *(const float4*)wsrc;
      const float4 w1 = *(const float4*)(wsrc + 4);
      f16x8 Af = {(f16)w0.x, (f16)w0.y, (f16)w0.z, (f16)w0.w,
                  (f16)w1.x, (f16)w1.y, (f16)w1.z, (f16)w1.w};
      o = __builtin_amdgcn_mfma_f32_16x16x32_f16(Af, Bf[kt], o, 0, 0, 0);
    }
    if (valid) {
      f32x4 oz = (m > 0) ? o : (f32x4){0.f, 0.f, 0.f, 0.f};
      *(f32x4*)(out + (size_t)g * 128 + ot * 16 + hi * 4) = oz;
    }
  }
}

// ---------------- host ----------------

extern "C" void kernel_launch(void* const* d_in, const int* in_sizes, int n_in,
                              void* d_out, int out_size, void* d_ws, size_t ws_size,
                              hipStream_t stream) {
  const float* msg   = (const float*)d_in[0];
  const float* t     = (const float*)d_in[1];
  const int*   indx  = (const int*)d_in[2];
  const float* W_ih  = (const float*)d_in[4];
  const float* W_hh  = (const float*)d_in[5];
  const float* b_ih  = (const float*)d_in[6];
  const float* b_hh  = (const float*)d_in[7];
  const float* W_mlp = (const float*)d_in[8];
  const float* b_mlp = (const float*)d_in[9];
  float* out = (float*)d_out;
  const int N   = in_sizes[0] / 128;
  const int dim = out_size / 128;
  const int nb  = (dim + 15) / 16;

  char* ws = (char*)d_ws;
  size_t o = 0;
  auto alloc = [&](size_t b) { size_t r = o; o = (o + b + 255) & ~(size_t)255; return r; };
  f16* gi16   = (f16*)(ws + alloc((size_t)N * G3 * 2));   // 153.6 MB
  u64* keys   = (u64*)(ws + alloc((size_t)N * 8));        // 1.6 MB
  u64* keys2  = (u64*)(ws + alloc((size_t)N * 8));        // 1.6 MB
  int* pos2g  = (int*)(ws + alloc((size_t)N * 4));        // 0.8 MB
  int* offs   = (int*)(ws + alloc((size_t)(dim + 1) * 4));
  int* loff   = (int*)(ws + alloc(513 * 4));
  int* order  = (int*)(ws + alloc((size_t)dim * 4));
  size_t meta_bytes = (size_t)(2 * dim + 1024) * 4;
  char* meta  = ws + alloc(meta_bytes);
  int* counts = (int*)meta;
  int* cursor = (int*)(meta + (size_t)dim * 4);
  int* lhist  = (int*)(meta + (size_t)2 * dim * 4);
  int* lcur   = (int*)(meta + (size_t)(2 * dim + 512) * 4);

  hipMemsetAsync(meta, 0, meta_bytes, stream);

  const int gN = (N + 255) / 256, gD = (dim + 255) / 256;
  hist_kernel<<<gN, 256, 0, stream>>>(indx, counts, N);
  scan_generic<<<1, 1024, 0, stream>>>(counts, offs, dim);
  scatter_kernel<<<gN, 256, 0, stream>>>(t, indx, offs, cursor, keys, pos2g, N);
  rank_kernel<<<gN, 256, 0, stream>>>(keys, pos2g, offs, counts, keys2, N);
  lenbin_kernel<<<gD, 256, 0, stream>>>(counts, lhist, dim);
  scan_generic<<<1, 1024, 0, stream>>>(lhist, loff, 512);
  lenscatter_kernel<<<gD, 256, 0, stream>>>(counts, loff, lcur, order, dim);

  hipFuncSetAttribute(reinterpret_cast<const void*>(gi_gemm),
                      hipFuncAttributeMaxDynamicSharedMemorySize, 131072);
  gi_gemm<<<(N + 127) / 128, 512, 131072, stream>>>(msg, W_ih, b_ih, b_hh, gi16, N);

  recur3<<<nb, 256, 0, stream>>>(gi16, keys2, offs, counts, W_hh, b_hh,
                                 W_mlp, b_mlp, order, out, dim);
}

// Round 5
// 387.670 us; speedup vs baseline: 2.0092x; 1.1777x over previous
//
#include <hip/hip_runtime.h>
#include <hip/hip_fp16.h>

typedef _Float16 f16;
typedef _Float16 f16x8 __attribute__((ext_vector_type(8)));
typedef _Float16 f16x4 __attribute__((ext_vector_type(4)));
typedef float    f32x4 __attribute__((ext_vector_type(4)));
typedef unsigned long long u64;
typedef unsigned int u32;

#define HIDDEN 128
#define G3     384   // 3*HIDDEN

__device__ inline float sigm(float x) { return 1.f / (1.f + __expf(-x)); }
__device__ inline float tanh_f(float x) {
  float ax = fabsf(x);
  float e  = __expf(2.f * ax);
  float r  = 1.f - 2.f / (e + 1.f);   // overflow -> 1.0, graceful
  return x < 0.f ? -r : r;
}

// ---------------- sorting pipeline ----------------

__global__ void hist_kernel(const int* __restrict__ idx, int* __restrict__ counts, int N) {
  int i = blockIdx.x * blockDim.x + threadIdx.x;
  if (i < N) atomicAdd(&counts[idx[i]], 1);
}

// fused: scan(counts)->offs, length-histogram, scan(lhist), length-ordered scatter -> order
__global__ __launch_bounds__(1024) void meta_kernel(const int* __restrict__ counts,
                                                    int* __restrict__ offs,
                                                    int* __restrict__ order, int dim) {
  __shared__ int wsum[16], wpre[16];
  __shared__ int lhist[512], loffs[512], lcur[512];
  const int tid = threadIdx.x, lane = tid & 63, wid = tid >> 6;
  for (int i = tid; i < 512; i += 1024) { lhist[i] = 0; lcur[i] = 0; }
  __syncthreads();
  // phase 1: exclusive scan counts -> offs (16 per thread) + length binning
  const int base_i = tid * 16;
  int loc[16];
  int s = 0;
#pragma unroll
  for (int u = 0; u < 16; u++) {
    int i = base_i + u;
    int x = (i < dim) ? counts[i] : 0;
    loc[u] = s; s += x;
    if (i < dim) atomicAdd(&lhist[511 - min(x, 511)], 1);
  }
  int inc = s;
#pragma unroll
  for (int d = 1; d < 64; d <<= 1) { int v = __shfl_up(inc, d, 64); if (lane >= d) inc += v; }
  if (lane == 63) wsum[wid] = inc;
  __syncthreads();
  if (wid == 0 && lane < 16) {
    int v = wsum[lane], p = v;
#pragma unroll
    for (int d = 1; d < 16; d <<= 1) { int q = __shfl_up(p, d, 16); if (lane >= d) p += q; }
    wpre[lane] = p - v;
  }
  __syncthreads();
  const int excl = wpre[wid] + inc - s;
#pragma unroll
  for (int u = 0; u < 16; u++) {
    int i = base_i + u;
    if (i < dim) offs[i] = excl + loc[u];
  }
  if (tid == 1023) offs[dim] = excl + s;
  __syncthreads();
  // phase 2: exclusive scan of lhist (512) in wave 0, 8 per lane
  if (wid == 0) {
    int l8[8]; int ss = 0;
#pragma unroll
    for (int u = 0; u < 8; u++) { l8[u] = ss; ss += lhist[lane * 8 + u]; }
    int inc2 = ss;
#pragma unroll
    for (int d = 1; d < 64; d <<= 1) { int v = __shfl_up(inc2, d, 64); if (lane >= d) inc2 += v; }
    const int e2 = inc2 - ss;
#pragma unroll
    for (int u = 0; u < 8; u++) loffs[lane * 8 + u] = e2 + l8[u];
  }
  __syncthreads();
  // phase 3: scatter group ids in descending-length order
#pragma unroll
  for (int u = 0; u < 16; u++) {
    int g = base_i + u;
    if (g < dim) {
      int b = 511 - min(counts[g], 511);
      int p = loffs[b] + atomicAdd(&lcur[b], 1);
      order[p] = g;
    }
  }
}

__global__ void scatter_kernel(const float* __restrict__ t, const int* __restrict__ idx,
                               const int* __restrict__ off, int* __restrict__ cursor,
                               u64* __restrict__ keys, int* __restrict__ pos2g, int N) {
  int i = blockIdx.x * blockDim.x + threadIdx.x;
  if (i >= N) return;
  int g = idx[i];
  int p = off[g] + atomicAdd(&cursor[g], 1);
  // t in [0,1): positive-float bits are order-preserving as uint; tie-break by i
  keys[p] = ((u64)__float_as_uint(t[i]) << 32) | (u32)i;
  pos2g[p] = g;
}

// parallel rank-select: each message counts smaller keys within its group
__global__ void rank_kernel(const u64* __restrict__ keys, const int* __restrict__ pos2g,
                            const int* __restrict__ off, const int* __restrict__ cnt,
                            u64* __restrict__ keys2, int N) {
  int p = blockIdx.x * blockDim.x + threadIdx.x;
  if (p >= N) return;
  int g = pos2g[p];
  int s = off[g], m = cnt[g];
  u64 k = keys[p];
  int r = 0;
  for (int q = 0; q < m; q++) r += (keys[s + q] < k);
  keys2[s + r] = k;
}

// ---------------- W_ih -> MFMA-fragment order, f16 ----------------
// wfrag[kc][t][lane][8]: value = W_ih[t*16 + (lane&15)][kc*32 + (lane>>4)*8 .. +8]

__global__ void prep_w(const float* __restrict__ W, f16* __restrict__ wfrag) {
  int v = blockIdx.x * blockDim.x + threadIdx.x;   // 6144 chunks
  if (v >= 6144) return;
  int lane = v & 63;
  int t = (v >> 6) % 24;
  int kc = v >> 6 >> 31 ? 0 : (v >> 6) / 24;       // kc = (v>>6)/24
  int col = t * 16 + (lane & 15);
  int ks = kc * 32 + (lane >> 4) * 8;
  const float* src = W + (size_t)col * 128 + ks;
  const float4 s0 = *(const float4*)src;
  const float4 s1 = *(const float4*)(src + 4);
  *(f16x8*)(wfrag + (size_t)v * 8) =
      (f16x8){(f16)s0.x, (f16)s0.y, (f16)s0.z, (f16)s0.w,
              (f16)s1.x, (f16)s1.y, (f16)s1.z, (f16)s1.w};
}

// ---------------- gi = msg @ W_ih^T + bias — LDS-free, register-B ----------------
// wave = 32 rows x 192 cols (col-half ch). bias = b_ih + b_hh (r,z) / b_ih (n).

__global__ __launch_bounds__(256, 2) void gi_gemm2(const float* __restrict__ A32, // [N][128]
                                                   const f16* __restrict__ wfrag,
                                                   const float* __restrict__ b_ih,
                                                   const float* __restrict__ b_hh,
                                                   f16* __restrict__ GI, int N) {
  const int tid = threadIdx.x;
  const int w = blockIdx.x * 4 + (tid >> 6);
  const int lane = tid & 63;
  const int nrg = (N + 31) >> 5;
  const int rowgrp = w >> 1, ch = w & 1;
  if (rowgrp >= nrg) return;
  const int r0 = rowgrp * 32;
  const int fr = lane & 15, kg = lane >> 4;

  f32x4 acc[2][12];
#pragma unroll
  for (int mi = 0; mi < 2; mi++)
#pragma unroll
    for (int nt = 0; nt < 12; nt++) acc[mi][nt] = (f32x4){0.f, 0.f, 0.f, 0.f};

#pragma unroll
  for (int kc = 0; kc < 4; kc++) {
    // A-frags direct from global (f32 -> f16)
    f16x8 a[2];
#pragma unroll
    for (int mi = 0; mi < 2; mi++) {
      int row = r0 + mi * 16 + fr; if (row >= N) row = N - 1;
      const float* p = A32 + (size_t)row * 128 + kc * 32 + kg * 8;
      const float4 s0 = *(const float4*)p;
      const float4 s1 = *(const float4*)(p + 4);
      a[mi] = (f16x8){(f16)s0.x, (f16)s0.y, (f16)s0.z, (f16)s0.w,
                      (f16)s1.x, (f16)s1.y, (f16)s1.z, (f16)s1.w};
    }
    // B-frags from fragment-ordered W (L2-hot, lane-linear)
    f16x8 b[12];
#pragma unroll
    for (int nt = 0; nt < 12; nt++)
      b[nt] = *(const f16x8*)(wfrag + ((size_t)((kc * 24 + ch * 12 + nt) * 64 + lane)) * 8);
#pragma unroll
    for (int mi = 0; mi < 2; mi++)
#pragma unroll
      for (int nt = 0; nt < 12; nt++)
        acc[mi][nt] = __builtin_amdgcn_mfma_f32_16x16x32_f16(a[mi], b[nt], acc[mi][nt], 0, 0, 0);
  }
  // epilogue: C/D col = lane&15 (within tile), row = kg*4 + q
#pragma unroll
  for (int nt = 0; nt < 12; nt++) {
    int col = ch * 192 + nt * 16 + fr;
    float bi = b_ih[col] + (col < 256 ? b_hh[col] : 0.f);
#pragma unroll
    for (int mi = 0; mi < 2; mi++)
#pragma unroll
      for (int q = 0; q < 4; q++) {
        int row = r0 + mi * 16 + kg * 4 + q;
        if (row < N) GI[(size_t)row * G3 + col] = (f16)(acc[mi][nt][q] + bi);
      }
  }
}

// ---------------- batched GRU recurrence v3: one batch (16 chains) per block ----------------
// 4 waves cooperate; wave q owns gh tiles {2q,2q+1} of each gate part (r,z,n) = exactly the
// h-rows [32q,32q+32) it updates. W_hh A-frags permanently in registers (96 VGPR/wave).
// h crosses waves via 8 KB double-buffered LDS (f16, XOR-swizzled). One barrier per step.

__global__ __launch_bounds__(256) void recur3(
    const f16* __restrict__ GI, const u64* __restrict__ keys,
    const int* __restrict__ off, const int* __restrict__ cnt,
    const float* __restrict__ W_hh, const float* __restrict__ b_hh,
    const float* __restrict__ W_mlp, const float* __restrict__ b_mlp,
    const int* __restrict__ order, float* __restrict__ out, int dim) {
  __shared__ __align__(16) f16 hB[2][16 * 128];  // [parity][c][k] swizzled
  const int tid = threadIdx.x;
  const int wq = tid >> 6, lane = tid & 63;
  const int c = lane & 15, hi = lane >> 4;   // chain / row-quarter (also A-frag fr/kg)

  // ---- W_hh A-frags into registers: tiles {2q,2q+1, +8, +16} x kt 0..3 ----
  f16x8 A[6][4];
#pragma unroll
  for (int i = 0; i < 6; i++) {
    const int mt = 2 * wq + (i >> 1) * 8 + (i & 1);   // i: 0,1->r  2,3->z  4,5->n
#pragma unroll
    for (int kt = 0; kt < 4; kt++) {
      const float* src = W_hh + (size_t)(mt * 16 + c) * 128 + kt * 32 + hi * 8;
      const float4 s0 = *(const float4*)src;
      const float4 s1 = *(const float4*)(src + 4);
      A[i][kt] = (f16x8){(f16)s0.x, (f16)s0.y, (f16)s0.z, (f16)s0.w,
                         (f16)s1.x, (f16)s1.y, (f16)s1.z, (f16)s1.w};
    }
  }
  // n-gate bias for this wave's rows
  const f32x4 bhn0 = *(const f32x4*)(b_hh + 256 + (2 * wq) * 16 + hi * 4);
  const f32x4 bhn1 = *(const f32x4*)(b_hh + 256 + (2 * wq + 1) * 16 + hi * 4);

  // ---- chain metadata (per lane: chain c) ----
  const int oidx = blockIdx.x * 16 + c;
  const bool valid = (oidx < dim);
  const int g = valid ? order[oidx] : 0;
  const int m = valid ? cnt[g] : 0;
  const int s = valid ? off[g] : 0;
  int L = m;
#pragma unroll
  for (int d = 1; d < 16; d <<= 1) L = max(L, __shfl_xor(L, d, 16));

  // ---- init h = 0 (f32 master regs + LDS buf 0) ----
  float h0[8];
#pragma unroll
  for (int i = 0; i < 8; i++) h0[i] = 0.f;
  const f16x4 z4 = {(f16)0.f, (f16)0.f, (f16)0.f, (f16)0.f};
  *(f16x4*)&hB[0][c * 128 + (((2 * wq) ^ (c & 7)) * 16) + hi * 4] = z4;
  *(f16x4*)&hB[0][c * 128 + (((2 * wq + 1) ^ (c & 7)) * 16) + hi * 4] = z4;
  __syncthreads();

  const u32* keysLo = (const u32*)keys;
  const int go_r = 2 * wq * 16 + hi * 4;   // gi offset base (r part) for this lane's rows
  // gi for step 0 + key for step 1
  u32 mid = keysLo[2 * ((m > 0) ? s : 0)];
  const f16* gp0 = GI + (size_t)mid * G3 + go_r;
  f16x4 gr0 = *(const f16x4*)(gp0);
  f16x4 gr1 = *(const f16x4*)(gp0 + 16);
  f16x4 gz0 = *(const f16x4*)(gp0 + 128);
  f16x4 gz1 = *(const f16x4*)(gp0 + 144);
  f16x4 gn0 = *(const f16x4*)(gp0 + 256);
  f16x4 gn1 = *(const f16x4*)(gp0 + 272);
  u32 midn = keysLo[2 * ((m > 0) ? (s + min(1, m - 1)) : 0)];

  for (int st = 0; st < L; ++st) {
    // prefetch gi for st+1 and key for st+2
    const f16* gpn = GI + (size_t)midn * G3 + go_r;
    f16x4 ngr0 = *(const f16x4*)(gpn);
    f16x4 ngr1 = *(const f16x4*)(gpn + 16);
    f16x4 ngz0 = *(const f16x4*)(gpn + 128);
    f16x4 ngz1 = *(const f16x4*)(gpn + 144);
    f16x4 ngn0 = *(const f16x4*)(gpn + 256);
    f16x4 ngn1 = *(const f16x4*)(gpn + 272);
    u32 midn2 = keysLo[2 * ((m > 0) ? (s + min(st + 2, m - 1)) : 0)];

    // B frags: h of all 16 chains from LDS buf[st&1]
    const f16* hr = hB[st & 1];
    f16x8 B[4];
#pragma unroll
    for (int kt = 0; kt < 4; kt++)
      B[kt] = *(const f16x8*)&hr[c * 128 + (((2 * kt + (hi >> 1)) ^ (c & 7)) * 16) + (hi & 1) * 8];

    // gh tiles (C in registers; A in registers; zero C-init)
    f32x4 C[6];
#pragma unroll
    for (int i = 0; i < 6; i++) C[i] = (f32x4){0.f, 0.f, 0.f, 0.f};
#pragma unroll
    for (int i = 0; i < 6; i++)
#pragma unroll
      for (int kt = 0; kt < 4; kt++)
        C[i] = __builtin_amdgcn_mfma_f32_16x16x32_f16(A[i][kt], B[kt], C[i], 0, 0, 0);

    // gates for this wave's 8 h-rows (2 tiles x 4)
    const bool act = (st < m);
#pragma unroll
    for (int q_ = 0; q_ < 4; q_++) {
      float r = sigm((float)gr0[q_] + C[0][q_]);
      float z = sigm((float)gz0[q_] + C[2][q_]);
      float n = tanh_f((float)gn0[q_] + r * (C[4][q_] + bhn0[q_]));
      if (act) h0[q_] = (1.f - z) * n + z * h0[q_];
      float r2 = sigm((float)gr1[q_] + C[1][q_]);
      float z2 = sigm((float)gz1[q_] + C[3][q_]);
      float n2 = tanh_f((float)gn1[q_] + r2 * (C[5][q_] + bhn1[q_]));
      if (act) h0[4 + q_] = (1.f - z2) * n2 + z2 * h0[4 + q_];
    }
    // write new h into buf[(st+1)&1]
    f16* hw = hB[(st + 1) & 1];
    *(f16x4*)&hw[c * 128 + (((2 * wq) ^ (c & 7)) * 16) + hi * 4] =
        (f16x4){(f16)h0[0], (f16)h0[1], (f16)h0[2], (f16)h0[3]};
    *(f16x4*)&hw[c * 128 + (((2 * wq + 1) ^ (c & 7)) * 16) + hi * 4] =
        (f16x4){(f16)h0[4], (f16)h0[5], (f16)h0[6], (f16)h0[7]};
    __syncthreads();

    gr0 = ngr0; gr1 = ngr1; gz0 = ngz0; gz1 = ngz1; gn0 = ngn0; gn1 = ngn1;
    mid = midn; midn = midn2;
  }

  // ---- fused MLP: out = h @ W_mlp^T + b_mlp ; empty nodes -> 0 ----
  const f16* hf = hB[L & 1];
  f16x8 Bf[4];
#pragma unroll
  for (int kt = 0; kt < 4; kt++)
    Bf[kt] = *(const f16x8*)&hf[c * 128 + (((2 * kt + (hi >> 1)) ^ (c & 7)) * 16) + (hi & 1) * 8];
#pragma unroll
  for (int oi = 0; oi < 2; oi++) {
    const int ot = 2 * wq + oi;
    f32x4 o = *(const f32x4*)(b_mlp + ot * 16 + hi * 4);
#pragma unroll
    for (int kt = 0; kt < 4; kt++) {
      const float* wsrc = W_mlp + (size_t)(ot * 16 + c) * 128 + kt * 32 + hi * 8;
      const float4 w0 = *(const float4*)wsrc;
      const float4 w1 = *(const float4*)(wsrc + 4);
      f16x8 Af = {(f16)w0.x, (f16)w0.y, (f16)w0.z, (f16)w0.w,
                  (f16)w1.x, (f16)w1.y, (f16)w1.z, (f16)w1.w};
      o = __builtin_amdgcn_mfma_f32_16x16x32_f16(Af, Bf[kt], o, 0, 0, 0);
    }
    if (valid) {
      f32x4 oz = (m > 0) ? o : (f32x4){0.f, 0.f, 0.f, 0.f};
      *(f32x4*)(out + (size_t)g * 128 + ot * 16 + hi * 4) = oz;
    }
  }
}

// ---------------- host ----------------

extern "C" void kernel_launch(void* const* d_in, const int* in_sizes, int n_in,
                              void* d_out, int out_size, void* d_ws, size_t ws_size,
                              hipStream_t stream) {
  const float* msg   = (const float*)d_in[0];
  const float* t     = (const float*)d_in[1];
  const int*   indx  = (const int*)d_in[2];
  const float* W_ih  = (const float*)d_in[4];
  const float* W_hh  = (const float*)d_in[5];
  const float* b_ih  = (const float*)d_in[6];
  const float* b_hh  = (const float*)d_in[7];
  const float* W_mlp = (const float*)d_in[8];
  const float* b_mlp = (const float*)d_in[9];
  float* out = (float*)d_out;
  const int N   = in_sizes[0] / 128;
  const int dim = out_size / 128;
  const int nb  = (dim + 15) / 16;

  char* ws = (char*)d_ws;
  size_t o = 0;
  auto alloc = [&](size_t b) { size_t r = o; o = (o + b + 255) & ~(size_t)255; return r; };
  f16* gi16   = (f16*)(ws + alloc((size_t)N * G3 * 2));   // 153.6 MB
  u64* keys   = (u64*)(ws + alloc((size_t)N * 8));        // 1.6 MB
  u64* keys2  = (u64*)(ws + alloc((size_t)N * 8));        // 1.6 MB
  int* pos2g  = (int*)(ws + alloc((size_t)N * 4));        // 0.8 MB
  int* offs   = (int*)(ws + alloc((size_t)(dim + 1) * 4));
  int* order  = (int*)(ws + alloc((size_t)dim * 4));
  f16* wfrag  = (f16*)(ws + alloc(6144 * 8 * 2));         // 96 KB
  size_t meta_bytes = (size_t)(2 * dim) * 4;
  char* meta  = ws + alloc(meta_bytes);
  int* counts = (int*)meta;
  int* cursor = (int*)(meta + (size_t)dim * 4);

  hipMemsetAsync(meta, 0, meta_bytes, stream);

  const int gN = (N + 255) / 256;
  prep_w<<<24, 256, 0, stream>>>(W_ih, wfrag);
  hist_kernel<<<gN, 256, 0, stream>>>(indx, counts, N);
  meta_kernel<<<1, 1024, 0, stream>>>(counts, offs, order, dim);
  scatter_kernel<<<gN, 256, 0, stream>>>(t, indx, offs, cursor, keys, pos2g, N);
  rank_kernel<<<gN, 256, 0, stream>>>(keys, pos2g, offs, counts, keys2, N);

  const int nrg = (N + 31) / 32;                 // 32-row groups
  const int nwaves = nrg * 2;                    // x2 col-halves
  gi_gemm2<<<(nwaves + 3) / 4, 256, 0, stream>>>(msg, wfrag, b_ih, b_hh, gi16, N);

  recur3<<<nb, 256, 0, stream>>>(gi16, keys2, offs, counts, W_hh, b_hh,
                                 W_mlp, b_mlp, order, out, dim);
}

// Round 6
// 350.055 us; speedup vs baseline: 2.2251x; 1.1075x over previous
//
#include <hip/hip_runtime.h>
#include <hip/hip_fp16.h>

typedef _Float16 f16;
typedef _Float16 f16x8 __attribute__((ext_vector_type(8)));
typedef _Float16 f16x4 __attribute__((ext_vector_type(4)));
typedef float    f32x4 __attribute__((ext_vector_type(4)));
typedef unsigned long long u64;
typedef unsigned int u32;

#define HIDDEN 128
#define G3     384   // 3*HIDDEN

__device__ inline float sigm(float x) { return 1.f / (1.f + __expf(-x)); }
__device__ inline float tanh_f(float x) {
  float ax = fabsf(x);
  float e  = __expf(2.f * ax);
  float r  = 1.f - 2.f / (e + 1.f);   // overflow -> 1.0, graceful
  return x < 0.f ? -r : r;
}
__device__ inline f16x4 cvt4(float4 v) {
  return (f16x4){(f16)v.x, (f16)v.y, (f16)v.z, (f16)v.w};
}
__device__ inline f16x8 cvt8(float4 a, float4 b) {
  return (f16x8){(f16)a.x, (f16)a.y, (f16)a.z, (f16)a.w,
                 (f16)b.x, (f16)b.y, (f16)b.z, (f16)b.w};
}
__device__ inline f32x4 ld4(const float* p) { return *(const f32x4*)p; }

// ---------------- sorting pipeline ----------------

__global__ void hist_kernel(const int* __restrict__ idx, int* __restrict__ counts, int N) {
  int i = blockIdx.x * blockDim.x + threadIdx.x;
  if (i < N) atomicAdd(&counts[idx[i]], 1);
}

// fused: scan(counts)->offs, length-histogram, scan(lhist), length-ordered scatter -> order
__global__ __launch_bounds__(1024) void meta_kernel(const int* __restrict__ counts,
                                                    int* __restrict__ offs,
                                                    int* __restrict__ order, int dim) {
  __shared__ int wsum[16], wpre[16];
  __shared__ int lhist[512], loffs[512], lcur[512];
  const int tid = threadIdx.x, lane = tid & 63, wid = tid >> 6;
  for (int i = tid; i < 512; i += 1024) { lhist[i] = 0; lcur[i] = 0; }
  __syncthreads();
  // phase 1: exclusive scan counts -> offs (16 per thread) + length binning
  const int base_i = tid * 16;
  int loc[16];
  int s = 0;
#pragma unroll
  for (int u = 0; u < 16; u++) {
    int i = base_i + u;
    int x = (i < dim) ? counts[i] : 0;
    loc[u] = s; s += x;
    if (i < dim) atomicAdd(&lhist[511 - min(x, 511)], 1);
  }
  int inc = s;
#pragma unroll
  for (int d = 1; d < 64; d <<= 1) { int v = __shfl_up(inc, d, 64); if (lane >= d) inc += v; }
  if (lane == 63) wsum[wid] = inc;
  __syncthreads();
  if (wid == 0 && lane < 16) {
    int v = wsum[lane], p = v;
#pragma unroll
    for (int d = 1; d < 16; d <<= 1) { int q = __shfl_up(p, d, 16); if (lane >= d) p += q; }
    wpre[lane] = p - v;
  }
  __syncthreads();
  const int excl = wpre[wid] + inc - s;
#pragma unroll
  for (int u = 0; u < 16; u++) {
    int i = base_i + u;
    if (i < dim) offs[i] = excl + loc[u];
  }
  if (tid == 1023) offs[dim] = excl + s;
  __syncthreads();
  // phase 2: exclusive scan of lhist (512) in wave 0, 8 per lane
  if (wid == 0) {
    int l8[8]; int ss = 0;
#pragma unroll
    for (int u = 0; u < 8; u++) { l8[u] = ss; ss += lhist[lane * 8 + u]; }
    int inc2 = ss;
#pragma unroll
    for (int d = 1; d < 64; d <<= 1) { int v = __shfl_up(inc2, d, 64); if (lane >= d) inc2 += v; }
    const int e2 = inc2 - ss;
#pragma unroll
    for (int u = 0; u < 8; u++) loffs[lane * 8 + u] = e2 + l8[u];
  }
  __syncthreads();
  // phase 3: scatter group ids in descending-length order
#pragma unroll
  for (int u = 0; u < 16; u++) {
    int g = base_i + u;
    if (g < dim) {
      int b = 511 - min(counts[g], 511);
      int p = loffs[b] + atomicAdd(&lcur[b], 1);
      order[p] = g;
    }
  }
}

__global__ void scatter_kernel(const float* __restrict__ t, const int* __restrict__ idx,
                               const int* __restrict__ off, int* __restrict__ cursor,
                               u64* __restrict__ keys, int* __restrict__ pos2g, int N) {
  int i = blockIdx.x * blockDim.x + threadIdx.x;
  if (i >= N) return;
  int g = idx[i];
  int p = off[g] + atomicAdd(&cursor[g], 1);
  // t in [0,1): positive-float bits are order-preserving as uint; tie-break by i
  keys[p] = ((u64)__float_as_uint(t[i]) << 32) | (u32)i;
  pos2g[p] = g;
}

// parallel rank-select: each message counts smaller keys within its group
__global__ void rank_kernel(const u64* __restrict__ keys, const int* __restrict__ pos2g,
                            const int* __restrict__ off, const int* __restrict__ cnt,
                            u64* __restrict__ keys2, int N) {
  int p = blockIdx.x * blockDim.x + threadIdx.x;
  if (p >= N) return;
  int g = pos2g[p];
  int s = off[g], m = cnt[g];
  u64 k = keys[p];
  int r = 0;
  for (int q = 0; q < m; q++) r += (keys[s + q] < k);
  keys2[s + r] = k;
}

// ---------------- fused GRU recurrence v4: gi GEMM folded into the step ----------------
// 16 chains per block, 512 threads / 8 waves. Wave q owns gate rows [16q,16q+16) of each
// part (r,z,n): W_ih frags (48 VGPR) + W_hh frags (48 VGPR) live in registers. Per step:
// stage 16 current msg rows (f32->f16) into swizzled LDS (double-buffered, like h), then
// Cr = b_r + W_ih_r@msg + W_hh_r@h (one f32 accum chain), same for z; n keeps i/h parts
// separate (n = tanh(i_n + r*h_n)). One barrier per step. MLP fused as epilogue.

__global__ __launch_bounds__(512) void recur4(
    const float* __restrict__ msg, const u64* __restrict__ keys,
    const int* __restrict__ off, const int* __restrict__ cnt,
    const float* __restrict__ W_ih, const float* __restrict__ W_hh,
    const float* __restrict__ b_ih, const float* __restrict__ b_hh,
    const float* __restrict__ W_mlp, const float* __restrict__ b_mlp,
    const int* __restrict__ order, float* __restrict__ out, int dim) {
  __shared__ __align__(16) f16 hB[2][16 * 128];   // h state, [c][k] XOR-swizzled
  __shared__ __align__(16) f16 mB[2][16 * 128];   // current msg, same layout
  __shared__ int sArr[16], mArr[16];
  const int tid = threadIdx.x;
  const int q = tid >> 6, lane = tid & 63;
  const int c = lane & 15, hi = lane >> 4;   // chain / row-quarter
  const int ct = tid >> 5;                   // staging chain (0..15), 32 threads each
  const int j4 = (tid & 31) * 4;             // staging feature offset (f32 granularity)

  // ---- chain metadata ----
  const int oidx = blockIdx.x * 16 + c;
  const bool valid = (oidx < dim);
  const int g = valid ? order[oidx] : 0;
  const int m = valid ? cnt[g] : 0;
  const int s = (valid && m > 0) ? off[g] : 0;   // clamped: empty -> 0 (safe key index)
  if (tid < 16) { sArr[tid] = s; mArr[tid] = m; }
  int L = m;
#pragma unroll
  for (int d = 1; d < 16; d <<= 1) L = max(L, __shfl_xor(L, d, 16));

  // ---- weight A-frags into registers: part p (r,z,n), k-tile kt ----
  f16x8 Ai[3][4], Ah[3][4];
#pragma unroll
  for (int p = 0; p < 3; p++)
#pragma unroll
    for (int kt = 0; kt < 4; kt++) {
      const size_t ro = (size_t)(p * 128 + q * 16 + c) * 128 + kt * 32 + hi * 8;
      Ai[p][kt] = cvt8(*(const float4*)(W_ih + ro), *(const float4*)(W_ih + ro + 4));
      Ah[p][kt] = cvt8(*(const float4*)(W_hh + ro), *(const float4*)(W_hh + ro + 4));
    }
  // ---- biases for this lane's 4 rows (q*16 + hi*4 + 0..3) ----
  const int rb = q * 16 + hi * 4;
  const f32x4 bR  = ld4(b_ih + rb)       + ld4(b_hh + rb);
  const f32x4 bZ  = ld4(b_ih + 128 + rb) + ld4(b_hh + 128 + rb);
  const f32x4 bNi = ld4(b_ih + 256 + rb);
  const f32x4 bNh = ld4(b_hh + 256 + rb);

  // ---- init h = 0 ----
  float h0[4] = {0.f, 0.f, 0.f, 0.f};
  *(f16x4*)&hB[0][c * 128 + ((q ^ (c & 7)) * 16) + hi * 4] =
      (f16x4){(f16)0.f, (f16)0.f, (f16)0.f, (f16)0.f};
  __syncthreads();   // sArr/mArr + hB[0] visible

  const u32* keysLo = (const u32*)keys;
  const int sc = sArr[ct], mc = mArr[ct];
  // ---- stage msg for step 0 ----
  {
    const u32 mid0 = keysLo[2 * sc];
    const float4 v = *(const float4*)(msg + (size_t)mid0 * 128 + j4);
    const int tk = j4 >> 4;
    *(f16x4*)&mB[0][ct * 128 + ((tk ^ (ct & 7)) * 16) + (j4 & 15)] = cvt4(v);
  }
  __syncthreads();

  for (int st = 0; st < L; ++st) {
    // B-frags: h and msg of all 16 chains from LDS buf[st&1]
    const f16* hr = hB[st & 1];
    const f16* mr = mB[st & 1];
    f16x8 Bh[4], Bm[4];
#pragma unroll
    for (int kt = 0; kt < 4; kt++) {
      const int ad = c * 128 + (((2 * kt + (hi >> 1)) ^ (c & 7)) * 16) + (hi & 1) * 8;
      Bh[kt] = *(const f16x8*)&hr[ad];
      Bm[kt] = *(const f16x8*)&mr[ad];
    }
    // prefetch msg row for step st+1 (hidden under MFMAs)
    const bool stg = (st + 1 < L);
    float4 v;
    if (stg) {
      const int pos = sc + max(0, min(st + 1, mc - 1));
      const u32 midn = keysLo[2 * pos];
      v = *(const float4*)(msg + (size_t)midn * 128 + j4);
    }
    // gate pre-activations: 4 independent accumulator chains, 24 MFMAs
    f32x4 Cr = bR, Cz = bZ, Cni = bNi, Cnh = bNh;
#pragma unroll
    for (int kt = 0; kt < 4; kt++) Cr  = __builtin_amdgcn_mfma_f32_16x16x32_f16(Ai[0][kt], Bm[kt], Cr, 0, 0, 0);
#pragma unroll
    for (int kt = 0; kt < 4; kt++) Cr  = __builtin_amdgcn_mfma_f32_16x16x32_f16(Ah[0][kt], Bh[kt], Cr, 0, 0, 0);
#pragma unroll
    for (int kt = 0; kt < 4; kt++) Cz  = __builtin_amdgcn_mfma_f32_16x16x32_f16(Ai[1][kt], Bm[kt], Cz, 0, 0, 0);
#pragma unroll
    for (int kt = 0; kt < 4; kt++) Cz  = __builtin_amdgcn_mfma_f32_16x16x32_f16(Ah[1][kt], Bh[kt], Cz, 0, 0, 0);
#pragma unroll
    for (int kt = 0; kt < 4; kt++) Cni = __builtin_amdgcn_mfma_f32_16x16x32_f16(Ai[2][kt], Bm[kt], Cni, 0, 0, 0);
#pragma unroll
    for (int kt = 0; kt < 4; kt++) Cnh = __builtin_amdgcn_mfma_f32_16x16x32_f16(Ah[2][kt], Bh[kt], Cnh, 0, 0, 0);
    // gates + h update (freeze finished chains)
    const bool act = (st < m);
#pragma unroll
    for (int qq = 0; qq < 4; qq++) {
      float r = sigm(Cr[qq]);
      float z = sigm(Cz[qq]);
      float n = tanh_f(Cni[qq] + r * Cnh[qq]);
      if (act) h0[qq] = (1.f - z) * n + z * h0[qq];
    }
    // write h + staged msg into buf[(st+1)&1]
    *(f16x4*)&hB[(st + 1) & 1][c * 128 + ((q ^ (c & 7)) * 16) + hi * 4] =
        (f16x4){(f16)h0[0], (f16)h0[1], (f16)h0[2], (f16)h0[3]};
    if (stg) {
      const int tk = j4 >> 4;
      *(f16x4*)&mB[(st + 1) & 1][ct * 128 + ((tk ^ (ct & 7)) * 16) + (j4 & 15)] = cvt4(v);
    }
    __syncthreads();
  }

  // ---- fused MLP: out = h @ W_mlp^T + b_mlp ; empty nodes -> 0 ----
  const f16* hf = hB[L & 1];
  f16x8 Bf[4];
#pragma unroll
  for (int kt = 0; kt < 4; kt++) {
    const int ad = c * 128 + (((2 * kt + (hi >> 1)) ^ (c & 7)) * 16) + (hi & 1) * 8;
    Bf[kt] = *(const f16x8*)&hf[ad];
  }
  f32x4 o = ld4(b_mlp + q * 16 + hi * 4);
#pragma unroll
  for (int kt = 0; kt < 4; kt++) {
    const size_t wo = (size_t)(q * 16 + c) * 128 + kt * 32 + hi * 8;
    f16x8 Af = cvt8(*(const float4*)(W_mlp + wo), *(const float4*)(W_mlp + wo + 4));
    o = __builtin_amdgcn_mfma_f32_16x16x32_f16(Af, Bf[kt], o, 0, 0, 0);
  }
  if (valid) {
    const f32x4 oz = (m > 0) ? o : (f32x4){0.f, 0.f, 0.f, 0.f};
    *(f32x4*)(out + (size_t)g * 128 + q * 16 + hi * 4) = oz;
  }
}

// ---------------- host ----------------

extern "C" void kernel_launch(void* const* d_in, const int* in_sizes, int n_in,
                              void* d_out, int out_size, void* d_ws, size_t ws_size,
                              hipStream_t stream) {
  const float* msg   = (const float*)d_in[0];
  const float* t     = (const float*)d_in[1];
  const int*   indx  = (const int*)d_in[2];
  const float* W_ih  = (const float*)d_in[4];
  const float* W_hh  = (const float*)d_in[5];
  const float* b_ih  = (const float*)d_in[6];
  const float* b_hh  = (const float*)d_in[7];
  const float* W_mlp = (const float*)d_in[8];
  const float* b_mlp = (const float*)d_in[9];
  float* out = (float*)d_out;
  const int N   = in_sizes[0] / 128;
  const int dim = out_size / 128;
  const int nb  = (dim + 15) / 16;

  char* ws = (char*)d_ws;
  size_t o = 0;
  auto alloc = [&](size_t b) { size_t r = o; o = (o + b + 255) & ~(size_t)255; return r; };
  u64* keys   = (u64*)(ws + alloc((size_t)N * 8));        // 1.6 MB
  u64* keys2  = (u64*)(ws + alloc((size_t)N * 8));        // 1.6 MB
  int* pos2g  = (int*)(ws + alloc((size_t)N * 4));        // 0.8 MB
  int* offs   = (int*)(ws + alloc((size_t)(dim + 1) * 4));
  int* order  = (int*)(ws + alloc((size_t)dim * 4));
  size_t meta_bytes = (size_t)(2 * dim) * 4;
  char* meta  = ws + alloc(meta_bytes);
  int* counts = (int*)meta;
  int* cursor = (int*)(meta + (size_t)dim * 4);

  hipMemsetAsync(meta, 0, meta_bytes, stream);

  const int gN = (N + 255) / 256;
  hist_kernel<<<gN, 256, 0, stream>>>(indx, counts, N);
  meta_kernel<<<1, 1024, 0, stream>>>(counts, offs, order, dim);
  scatter_kernel<<<gN, 256, 0, stream>>>(t, indx, offs, cursor, keys, pos2g, N);
  rank_kernel<<<gN, 256, 0, stream>>>(keys, pos2g, offs, counts, keys2, N);

  recur4<<<nb, 512, 0, stream>>>(msg, keys2, offs, counts, W_ih, W_hh, b_ih, b_hh,
                                 W_mlp, b_mlp, order, out, dim);
}